// Round 11
// baseline (541.531 us; speedup 1.0000x reference)
//
#include <hip/hip_runtime.h>
#include <math.h>

#define BH 32
#define N_ 4096
#define D_ 64
#define M_ 256
#define L_ 16
#define DIM_ 512
#define K3_ 1536

typedef __attribute__((ext_vector_type(4))) float f32x4;
typedef __attribute__((ext_vector_type(8))) short s16x8;
typedef unsigned short ushort_t;

__device__ inline ushort_t f2bf(float f){
  union{float f; unsigned u;} v; v.f = f;
  unsigned r = v.u + 0x7fffu + ((v.u >> 16) & 1u);
  return (ushort_t)(r >> 16);
}
__device__ inline float bf2f(ushort_t b){
  union{unsigned u; float f;} v; v.u = ((unsigned)b) << 16; return v.f;
}

// async global->LDS, 16B per lane. LDS dest wave-uniform base + lane*16
// (linear); global src addr is per-lane (carries the swizzle).
__device__ inline void gl_lds16(const ushort_t* g, ushort_t* l){
  __builtin_amdgcn_global_load_lds(
      (const __attribute__((address_space(1))) unsigned int*)g,
      (__attribute__((address_space(3))) unsigned int*)l, 16, 0, 0);
}

// XCD-aware bijective block remap (T1). Requires nwg % 8 == 0.
__device__ inline int xcd_swz_bid(){
  int bid = blockIdx.x + gridDim.x*(blockIdx.y + gridDim.y*blockIdx.z);
  int nwg = gridDim.x*gridDim.y*gridDim.z;
  int cpx = nwg >> 3;
  return (bid & 7)*cpx + (bid >> 3);
}

// ---------- reduction helpers ----------
__device__ inline float wave_sum_all(float v){
  #pragma unroll
  for (int o=1;o<64;o<<=1) v += __shfl_xor(v,o,64);
  return v;
}
__device__ inline float wave_max(float v){
  #pragma unroll
  for (int o=32;o;o>>=1) v = fmaxf(v,__shfl_down(v,o,64));
  return v;
}
__device__ inline float blk_max256(float v, float* sm){
  v = wave_max(v);
  int lane = threadIdx.x & 63, wid = threadIdx.x >> 6;
  if (lane==0) sm[wid]=v;
  __syncthreads();
  float r = fmaxf(fmaxf(sm[0],sm[1]),fmaxf(sm[2],sm[3]));
  __syncthreads();
  return r;
}

// ---------- 1. LayerNorm -> bf16: one wave per row, no barriers ----------
__global__ __launch_bounds__(256) void ln2_k(const float* __restrict__ x,
    const float* __restrict__ g, const float* __restrict__ bt, ushort_t* __restrict__ xn){
  int t = threadIdx.x, lane = t & 63, w = t >> 6;
  size_t row = (size_t)blockIdx.x*4 + w;
  const float* xr = x + row*DIM_;
  f32x4 a = *(const f32x4*)&xr[lane*8];
  f32x4 b = *(const f32x4*)&xr[lane*8+4];
  float s = a[0]+a[1]+a[2]+a[3]+b[0]+b[1]+b[2]+b[3];
  float mu = wave_sum_all(s) * (1.f/DIM_);
  float d[8];
  #pragma unroll
  for (int i=0;i<4;i++){ d[i] = a[i]-mu; d[i+4] = b[i]-mu; }
  float vs = 0.f;
  #pragma unroll
  for (int i=0;i<8;i++) vs += d[i]*d[i];
  float var = wave_sum_all(vs) * (1.f/DIM_);
  float rs = rsqrtf(var + 1e-5f);
  f32x4 g0 = *(const f32x4*)&g[lane*8], g1 = *(const f32x4*)&g[lane*8+4];
  f32x4 b0 = *(const f32x4*)&bt[lane*8], b1 = *(const f32x4*)&bt[lane*8+4];
  ushort_t tmp[8];
  #pragma unroll
  for (int i=0;i<4;i++){
    tmp[i]   = f2bf(d[i]*rs*g0[i]   + b0[i]);
    tmp[i+4] = f2bf(d[i+4]*rs*g1[i] + b1[i]);
  }
  *(uint4*)&xn[row*DIM_ + lane*8] = *(uint4*)tmp;
}

// ---------- merged weight transpose: bx<24 -> w_qkv (512x1536), else w_out (512x512) ----------
__global__ __launch_bounds__(256) void twbw_k(const float* __restrict__ wqkv,
    ushort_t* __restrict__ wqkvT, const float* __restrict__ wout,
    ushort_t* __restrict__ woutT){
  __shared__ ushort_t tile[64][66];
  const float* src; ushort_t* dst; int R = 512, C;
  int bx = blockIdx.x;
  if (bx < 24){ src = wqkv; dst = wqkvT; C = 1536; }
  else        { src = wout; dst = woutT; C = 512; bx -= 24; }
  int r0 = blockIdx.y*64, c0 = bx*64;
  int t = threadIdx.x, c = t & 63, r4 = t >> 6;
  #pragma unroll
  for (int i=0;i<16;i++){
    int rr = r4 + i*4;
    tile[c][rr] = f2bf(src[(size_t)(r0+rr)*C + (c0+c)]);
  }
  __syncthreads();
  #pragma unroll
  for (int i=0;i<16;i++){
    int cc = r4 + i*4;
    dst[(size_t)(c0+cc)*R + (r0 + c)] = tile[cc][c];
  }
}
// ---------- transpose fp32 [R][C] -> bf16 [C][R], batched via z ----------
__global__ __launch_bounds__(256) void twb_k(const float* __restrict__ src,
    ushort_t* __restrict__ dst, int R, int C){
  __shared__ ushort_t tile[64][66];
  size_t boff = (size_t)blockIdx.z * R * C;
  int r0 = blockIdx.y*64, c0 = blockIdx.x*64;
  int t = threadIdx.x, c = t & 63, r4 = t >> 6;
  #pragma unroll
  for (int i=0;i<16;i++){
    int rr = r4 + i*4;
    tile[c][rr] = f2bf(src[boff + (size_t)(r0+rr)*C + (c0+c)]);
  }
  __syncthreads();
  #pragma unroll
  for (int i=0;i<16;i++){
    int cc = r4 + i*4;
    dst[boff + (size_t)(c0+cc)*R + (r0 + c)] = tile[cc][c];
  }
}

// ---------- 2. QKV GEMM bf16 MFMA; V blocks also emit vT (fused transpose) ----------
__global__ __launch_bounds__(256) void gemm_qkv_k(const ushort_t* __restrict__ A,
    const ushort_t* __restrict__ Bt, ushort_t* __restrict__ qb, ushort_t* __restrict__ kb,
    ushort_t* __restrict__ vb, ushort_t* __restrict__ vT){
  __shared__ __align__(16) ushort_t As[128*64];
  __shared__ __align__(16) ushort_t Bs[128*64];
  int t = threadIdx.x;
  int lane = t & 63, wave = t >> 6;
  int l16 = lane & 15, quad = lane >> 4;
  int wm = (wave & 1) * 64, wn = (wave >> 1) * 64;
  int swz = xcd_swz_bid();
  int bx = swz % gridDim.x, by = swz / gridDim.x;
  int row0 = by * 128, col0 = bx * 128;
  f32x4 acc[4][4];
  #pragma unroll
  for (int i=0;i<4;i++)
    #pragma unroll
    for (int j=0;j<4;j++) acc[i][j] = (f32x4){0.f,0.f,0.f,0.f};
  int lr = lane >> 3, lc = lane & 7;
  int scol = (lc ^ lr) * 8;
  int rx7 = l16 & 7;
  for (int k0=0;k0<DIM_;k0+=64){
    __syncthreads();
    #pragma unroll
    for (int p=0;p<4;p++){
      int r = wave*8 + p*32;
      gl_lds16(&A [(size_t)(row0+r+lr)*DIM_ + k0 + scol], &As[(size_t)r*64]);
      gl_lds16(&Bt[(size_t)(col0+r+lr)*DIM_ + k0 + scol], &Bs[(size_t)r*64]);
    }
    __syncthreads();
    s16x8 af[4][2], bf[4][2];
    #pragma unroll
    for (int mt=0;mt<4;mt++)
      #pragma unroll
      for (int kk=0;kk<2;kk++)
        af[mt][kk] = *(const s16x8*)&As[(wm + mt*16 + l16)*64 + (((kk*4+quad)^rx7)*8)];
    #pragma unroll
    for (int nt=0;nt<4;nt++)
      #pragma unroll
      for (int kk=0;kk<2;kk++)
        bf[nt][kk] = *(const s16x8*)&Bs[(wn + nt*16 + l16)*64 + (((kk*4+quad)^rx7)*8)];
    #pragma unroll
    for (int mt=0;mt<4;mt++)
      #pragma unroll
      for (int nt=0;nt<4;nt++)
        #pragma unroll
        for (int kk=0;kk<2;kk++)
          acc[mt][nt] = __builtin_amdgcn_mfma_f32_16x16x32_bf16(af[mt][kk], bf[nt][kk], acc[mt][nt], 0,0,0);
  }
  #pragma unroll
  for (int mt=0;mt<4;mt++){
    #pragma unroll
    for (int nt=0;nt<4;nt++){
      int rowb = row0 + wm + mt*16 + quad*4;
      int col = col0 + wn + nt*16 + l16;
      int b = rowb >> 12, n = rowb & 4095;
      int which = col >> 9, rem = col & 511;
      int h = rem >> 6, d = rem & 63;
      int bh = (b<<3)+h;
      ushort_t th[4];
      #pragma unroll
      for (int reg=0;reg<4;reg++){
        float val = acc[mt][nt][reg];
        size_t dst = ((size_t)bh*N_ + n + reg)*D_ + d;
        if (which==0)      qb[dst] = f2bf(val*0.125f);
        else if (which==1) kb[dst] = f2bf(val);
        else { ushort_t hv = f2bf(val); vb[dst] = hv; th[reg] = hv; }
      }
      if (which==2){
        uint2 w;
        w.x = (unsigned)th[0] | ((unsigned)th[1]<<16);
        w.y = (unsigned)th[2] | ((unsigned)th[3]<<16);
        *(uint2*)&vT[((size_t)bh*D_ + d)*N_ + n] = w;
      }
    }
  }
}

// ---------- final GEMM v5: 64x64 tiles, gl_lds, 2048 blocks = 8/CU ----------
__global__ __launch_bounds__(256) void final4_k(const ushort_t* __restrict__ A,
    const ushort_t* __restrict__ Bt, const float* __restrict__ bo,
    const float* __restrict__ x, float* __restrict__ y){
  __shared__ __align__(16) ushort_t As[64*64];
  __shared__ __align__(16) ushort_t Bs[64*64];
  int t = threadIdx.x;
  int lane = t & 63, wave = t >> 6;
  int l16 = lane & 15, quad = lane >> 4;
  int swz = xcd_swz_bid();
  int bx = swz % gridDim.x, by = swz / gridDim.x;
  int row0 = by * 64, col0 = bx * 64;
  f32x4 acc[4];
  #pragma unroll
  for (int j=0;j<4;j++) acc[j] = (f32x4){0.f,0.f,0.f,0.f};
  int lr = lane >> 3, lc = lane & 7;
  int scol = (lc ^ lr) * 8;
  int rx7 = l16 & 7;
  for (int k0=0;k0<DIM_;k0+=64){
    __syncthreads();
    #pragma unroll
    for (int p=0;p<2;p++){
      int r = wave*8 + p*32;
      gl_lds16(&A [(size_t)(row0+r+lr)*DIM_ + k0 + scol], &As[(size_t)r*64]);
      gl_lds16(&Bt[(size_t)(col0+r+lr)*DIM_ + k0 + scol], &Bs[(size_t)r*64]);
    }
    __syncthreads();
    s16x8 af[2];
    #pragma unroll
    for (int kk=0;kk<2;kk++)
      af[kk] = *(const s16x8*)&As[(wave*16 + l16)*64 + (((kk*4+quad)^rx7)*8)];
    #pragma unroll
    for (int nt=0;nt<4;nt++){
      #pragma unroll
      for (int kk=0;kk<2;kk++){
        s16x8 bf = *(const s16x8*)&Bs[(nt*16 + l16)*64 + (((kk*4+quad)^rx7)*8)];
        acc[nt] = __builtin_amdgcn_mfma_f32_16x16x32_bf16(af[kk], bf, acc[nt], 0,0,0);
      }
    }
  }
  int rbase = row0 + wave*16 + quad*4;
  #pragma unroll
  for (int nt=0;nt<4;nt++){
    int col = col0 + nt*16 + l16;
    #pragma unroll
    for (int reg=0;reg<4;reg++){
      size_t o = (size_t)(rbase+reg)*DIM_ + col;
      y[o] = acc[nt][reg] + bo[col] + x[o];
    }
  }
}

// ---------- 3. landmark means (fp32 + bf16 h/l splits) ----------
__global__ void lmk_k(const ushort_t* __restrict__ q, const ushort_t* __restrict__ k,
                      float* __restrict__ ql, float* __restrict__ kl,
                      ushort_t* __restrict__ qlh, ushort_t* __restrict__ qll,
                      ushort_t* __restrict__ klh, ushort_t* __restrict__ kll){
  int idx = blockIdx.x*256 + threadIdx.x;
  int d = idx & 63, i = (idx >> 6) & 255, bh = idx >> 14;
  size_t base = ((size_t)bh*N_ + i*L_)*D_ + d;
  float sq=0.f, sk=0.f;
  #pragma unroll
  for (int tt=0;tt<L_;tt++){ sq += bf2f(q[base + (size_t)tt*D_]); sk += bf2f(k[base + (size_t)tt*D_]); }
  sq *= (1.f/L_); sk *= (1.f/L_);
  ql[idx] = sq; kl[idx] = sk;
  ushort_t qh = f2bf(sq), kh = f2bf(sk);
  qlh[idx] = qh; qll[idx] = f2bf(sq - bf2f(qh));
  klh[idx] = kh; kll[idx] = f2bf(sk - bf2f(kh));
}

// ---------- 4. attn2 via split-bf16 MFMA, fused col sums ----------
__global__ __launch_bounds__(256) void attn2m_k(
    const ushort_t* __restrict__ qlh, const ushort_t* __restrict__ qll,
    const ushort_t* __restrict__ klh, const ushort_t* __restrict__ kll,
    float* __restrict__ a2f, ushort_t* __restrict__ a2h, ushort_t* __restrict__ a2l,
    float* __restrict__ cs){
  int bh = blockIdx.y;
  int t = threadIdx.x, wave = t >> 6, lane = t & 63;
  int l16 = lane & 15, quad = lane >> 4;
  size_t mo = (size_t)bh*M_*M_;
  int rowtile = blockIdx.x*32 + wave*16;
  size_t qbase = ((size_t)bh*M_ + rowtile + l16)*D_;
  s16x8 qh0 = *(const s16x8*)&qlh[qbase + quad*8];
  s16x8 qh1 = *(const s16x8*)&qlh[qbase + 32 + quad*8];
  s16x8 qv0 = *(const s16x8*)&qll[qbase + quad*8];
  s16x8 qv1 = *(const s16x8*)&qll[qbase + 32 + quad*8];
  f32x4 s[16];
  #pragma unroll
  for (int kt=0;kt<16;kt++){
    size_t kb = ((size_t)bh*M_ + kt*16 + l16)*D_;
    s16x8 kh0 = *(const s16x8*)&klh[kb + quad*8];
    s16x8 kh1 = *(const s16x8*)&klh[kb + 32 + quad*8];
    s16x8 kv0 = *(const s16x8*)&kll[kb + quad*8];
    s16x8 kv1 = *(const s16x8*)&kll[kb + 32 + quad*8];
    f32x4 z = (f32x4){0.f,0.f,0.f,0.f};
    z = __builtin_amdgcn_mfma_f32_16x16x32_bf16(qh0, kh0, z, 0,0,0);
    z = __builtin_amdgcn_mfma_f32_16x16x32_bf16(qh1, kh1, z, 0,0,0);
    z = __builtin_amdgcn_mfma_f32_16x16x32_bf16(qh0, kv0, z, 0,0,0);
    z = __builtin_amdgcn_mfma_f32_16x16x32_bf16(qh1, kv1, z, 0,0,0);
    z = __builtin_amdgcn_mfma_f32_16x16x32_bf16(qv0, kh0, z, 0,0,0);
    z = __builtin_amdgcn_mfma_f32_16x16x32_bf16(qv1, kh1, z, 0,0,0);
    s[kt] = z;
  }
  float mx[4], inv[4];
  #pragma unroll
  for (int r=0;r<4;r++){
    float m = s[0][r];
    #pragma unroll
    for (int kt=1;kt<16;kt++) m = fmaxf(m, s[kt][r]);
    m = fmaxf(m, __shfl_xor(m, 1));
    m = fmaxf(m, __shfl_xor(m, 2));
    m = fmaxf(m, __shfl_xor(m, 4));
    m = fmaxf(m, __shfl_xor(m, 8));
    mx[r] = m;
  }
  float lsum[4] = {0.f,0.f,0.f,0.f};
  #pragma unroll
  for (int kt=0;kt<16;kt++){
    #pragma unroll
    for (int r=0;r<4;r++){
      float e = expf(s[kt][r] - mx[r]);
      s[kt][r] = e;
      lsum[r] += e;
    }
  }
  #pragma unroll
  for (int r=0;r<4;r++){
    float ls = lsum[r];
    ls += __shfl_xor(ls, 1);
    ls += __shfl_xor(ls, 2);
    ls += __shfl_xor(ls, 4);
    ls += __shfl_xor(ls, 8);
    inv[r] = 1.f/ls;
  }
  #pragma unroll
  for (int kt=0;kt<16;kt++){
    int c = kt*16 + l16;
    float csum = 0.f;
    #pragma unroll
    for (int r=0;r<4;r++){
      float p = s[kt][r]*inv[r];
      csum += p;
      size_t oi = mo + (size_t)(rowtile + quad*4 + r)*M_ + c;
      a2f[oi] = p;
      ushort_t hh = f2bf(p);
      a2h[oi] = hh;
      a2l[oi] = f2bf(p - bf2f(hh));
    }
    csum += __shfl_xor(csum, 16);
    csum += __shfl_xor(csum, 32);
    if (lane < 16) atomicAdd(&cs[(size_t)bh*M_ + c], csum);
  }
}

// ---------- initz v4: fused scal = 1/max(cs) (row sums are exactly 1) ----------
__global__ __launch_bounds__(256) void initz4_k(const float* __restrict__ a2,
    const float* __restrict__ cs,
    ushort_t* __restrict__ zh, ushort_t* __restrict__ zl,
    ushort_t* __restrict__ zTh, ushort_t* __restrict__ zTl){
  __shared__ float tile[64][65];
  __shared__ float sm[4];
  float cm = -1e30f;
  for (int i=threadIdx.x; i<BH*M_; i+=256) cm = fmaxf(cm, cs[i]);
  cm = blk_max256(cm, sm);
  float s = 1.f/cm;
  int bh = blockIdx.z;
  size_t mo = (size_t)bh*M_*M_;
  int r0 = blockIdx.y*64, c0 = blockIdx.x*64;
  int t = threadIdx.x, c = t & 63, r4 = t >> 6;
  #pragma unroll
  for (int i=0;i<16;i++){
    int rr = r4 + i*4;
    float v = a2[mo + (size_t)(r0+rr)*M_ + c0 + c] * s;
    tile[rr][c] = v;
    ushort_t hh = f2bf(v);
    size_t oi = mo + (size_t)(r0+rr)*M_ + c0 + c;
    zTh[oi] = hh;
    zTl[oi] = f2bf(v - bf2f(hh));
  }
  __syncthreads();
  #pragma unroll
  for (int i=0;i<16;i++){
    int zr = r4 + i*4;
    float v = tile[c][zr];
    size_t oi = mo + (size_t)(c0+zr)*M_ + r0 + c;
    ushort_t hh = f2bf(v);
    zh[oi] = hh;
    zl[oi] = f2bf(v - bf2f(hh));
  }
}

// ---------- Newton-Schulz GEMM: 64x64 tiles, global_load_lds staging ----------
template<bool HASCOEF, bool WN, bool WT, bool WF>
__global__ __launch_bounds__(256) void ns3_k(
    const ushort_t* __restrict__ Ah, const ushort_t* __restrict__ Al,
    const ushort_t* __restrict__ BTh, const ushort_t* __restrict__ BTl,
    float coef, float scale,
    ushort_t* __restrict__ Ch, ushort_t* __restrict__ Cl,
    ushort_t* __restrict__ CTh, ushort_t* __restrict__ CTl,
    float* __restrict__ Cf){
  __shared__ __align__(16) ushort_t Ahs[64*64];
  __shared__ __align__(16) ushort_t Als[64*64];
  __shared__ __align__(16) ushort_t Bhs[64*64];
  __shared__ __align__(16) ushort_t Bls[64*64];
  int swz = xcd_swz_bid();
  int bx = swz % gridDim.x; int rem = swz / gridDim.x;
  int by = rem % gridDim.y; int batch = rem / gridDim.y;
  size_t mo = (size_t)batch*M_*M_;
  int row0 = by*64, col0 = bx*64;
  int t = threadIdx.x, lane = t & 63, wave = t >> 6;
  int l16 = lane & 15, quad = lane >> 4;
  f32x4 acc[4];
  #pragma unroll
  for (int j=0;j<4;j++) acc[j] = (f32x4){0.f,0.f,0.f,0.f};
  int lr = lane >> 3, lc = lane & 7;
  int scol = (lc ^ lr) * 8;
  int rx7 = l16 & 7;
  for (int k0=0;k0<M_;k0+=64){
    __syncthreads();
    #pragma unroll
    for (int p=0;p<2;p++){
      int r = wave*8 + p*32;
      gl_lds16(&Ah [mo + (size_t)(row0+r+lr)*M_ + k0 + scol], &Ahs[(size_t)r*64]);
      gl_lds16(&Al [mo + (size_t)(row0+r+lr)*M_ + k0 + scol], &Als[(size_t)r*64]);
      gl_lds16(&BTh[mo + (size_t)(col0+r+lr)*M_ + k0 + scol], &Bhs[(size_t)r*64]);
      gl_lds16(&BTl[mo + (size_t)(col0+r+lr)*M_ + k0 + scol], &Bls[(size_t)r*64]);
    }
    __syncthreads();
    s16x8 fah[2], fal[2];
    #pragma unroll
    for (int kk=0;kk<2;kk++){
      fah[kk] = *(const s16x8*)&Ahs[(wave*16 + l16)*64 + (((kk*4+quad)^rx7)*8)];
      fal[kk] = *(const s16x8*)&Als[(wave*16 + l16)*64 + (((kk*4+quad)^rx7)*8)];
    }
    #pragma unroll
    for (int nt=0;nt<4;nt++){
      #pragma unroll
      for (int kk=0;kk<2;kk++){
        s16x8 fbh = *(const s16x8*)&Bhs[(nt*16 + l16)*64 + (((kk*4+quad)^rx7)*8)];
        s16x8 fbl = *(const s16x8*)&Bls[(nt*16 + l16)*64 + (((kk*4+quad)^rx7)*8)];
        acc[nt] = __builtin_amdgcn_mfma_f32_16x16x32_bf16(fah[kk], fbh, acc[nt], 0,0,0);
        acc[nt] = __builtin_amdgcn_mfma_f32_16x16x32_bf16(fah[kk], fbl, acc[nt], 0,0,0);
        acc[nt] = __builtin_amdgcn_mfma_f32_16x16x32_bf16(fal[kk], fbh, acc[nt], 0,0,0);
      }
    }
  }
  int rbase = row0 + wave*16 + quad*4;
  #pragma unroll
  for (int nt=0;nt<4;nt++){
    int c = col0 + nt*16 + l16;
    ushort_t th[4], tl[4];
    #pragma unroll
    for (int reg=0;reg<4;reg++){
      float a = acc[nt][reg];
      float base = 0.f;
      if (HASCOEF){
        size_t ai = mo + (size_t)(rbase+reg)*M_ + c;
        base = coef*(bf2f(Ah[ai]) + bf2f(Al[ai]));
      }
      float v = scale*(base - a);
      if (WF) Cf[mo + (size_t)(rbase+reg)*M_ + c] = v;
      ushort_t hh = f2bf(v);
      ushort_t ll = f2bf(v - bf2f(hh));
      if (WN){
        Ch[mo + (size_t)(rbase+reg)*M_ + c] = hh;
        Cl[mo + (size_t)(rbase+reg)*M_ + c] = ll;
      }
      th[reg] = hh; tl[reg] = ll;
    }
    if (WT){
      uint2 vh; vh.x = (unsigned)th[0] | ((unsigned)th[1]<<16); vh.y = (unsigned)th[2] | ((unsigned)th[3]<<16);
      uint2 vl; vl.x = (unsigned)tl[0] | ((unsigned)tl[1]<<16); vl.y = (unsigned)tl[2] | ((unsigned)tl[3]<<16);
      *(uint2*)&CTh[mo + (size_t)c*M_ + rbase] = vh;
      *(uint2*)&CTl[mo + (size_t)c*M_ + rbase] = vl;
    }
  }
}

// ---------- flash attention v8: transposed-QK + gl_lds K/V staging ----------
template<int ITERS, bool SCATTER>
__global__ __launch_bounds__(256) void attn8_k(const ushort_t* __restrict__ Q,
    const ushort_t* __restrict__ K, const ushort_t* __restrict__ VT,
    int nq, int nk,
    float* __restrict__ up, float* __restrict__ mst, float* __restrict__ lst,
    ushort_t* __restrict__ ob){
  __shared__ __align__(16) ushort_t Ks[64*64];
  __shared__ __align__(16) ushort_t Vs[64*64];
  __shared__ __align__(16) ushort_t Pb[4*16*76];
  int swz = xcd_swz_bid();
  int qblk = swz % gridDim.x; int rem0 = swz / gridDim.x;
  int half = rem0 % gridDim.y; int bh = rem0 / gridDim.y;
  int key0 = half * (ITERS*64);
  int t = threadIdx.x, wave = t >> 6, lane = t & 63;
  int l16 = lane & 15, quad = lane >> 4;
  size_t qbase = ((size_t)bh*nq + qblk*64 + wave*16 + l16)*D_;
  s16x8 qa0 = *(const s16x8*)&Q[qbase + quad*8];
  s16x8 qa1 = *(const s16x8*)&Q[qbase + 32 + quad*8];
  const ushort_t* Kb = K + (size_t)bh*nk*D_;
  const ushort_t* Vb = VT + (size_t)bh*D_*nk;
  ushort_t* Pw = &Pb[wave*16*76];
  int lr = lane >> 3, lc = lane & 7;
  int scol = (lc ^ lr) * 8;
  int rx7 = l16 & 7;
  float m_j = -1e30f, l_j = 0.f;
  f32x4 oacc[4];
  #pragma unroll
  for (int d=0;d<4;d++) oacc[d] = (f32x4){0.f,0.f,0.f,0.f};
  for (int it=0; it<ITERS; it++){
    int j0 = key0 + it*64;
    __syncthreads();
    #pragma unroll
    for (int p=0;p<2;p++){
      int r = wave*8 + p*32;
      gl_lds16(&Kb[(size_t)(j0+r+lr)*D_ + scol], &Ks[(size_t)r*64]);
      gl_lds16(&Vb[(size_t)(r+lr)*nk + j0 + scol], &Vs[(size_t)r*64]);
    }
    __syncthreads();
    f32x4 st[4];
    #pragma unroll
    for (int kt=0;kt<4;kt++){
      s16x8 b0 = *(const s16x8*)&Ks[(kt*16 + l16)*64 + ((quad^rx7)*8)];
      s16x8 b1 = *(const s16x8*)&Ks[(kt*16 + l16)*64 + (((4+quad)^rx7)*8)];
      f32x4 z = (f32x4){0.f,0.f,0.f,0.f};
      z = __builtin_amdgcn_mfma_f32_16x16x32_bf16(b0, qa0, z, 0,0,0);
      z = __builtin_amdgcn_mfma_f32_16x16x32_bf16(b1, qa1, z, 0,0,0);
      st[kt] = z;
    }
    float mx = st[0][0];
    #pragma unroll
    for (int kt=0;kt<4;kt++)
      #pragma unroll
      for (int r=0;r<4;r++) mx = fmaxf(mx, st[kt][r]);
    mx = fmaxf(mx, __shfl_xor(mx, 16));
    mx = fmaxf(mx, __shfl_xor(mx, 32));
    float mn = fmaxf(m_j, mx);
    float alpha = __expf(m_j - mn);
    m_j = mn;
    float lsum = 0.f;
    #pragma unroll
    for (int kt=0;kt<4;kt++){
      ushort_t pk[4];
      #pragma unroll
      for (int r=0;r<4;r++){
        float p = __expf(st[kt][r] - mn);
        lsum += p;
        pk[r] = f2bf(p);
      }
      uint2 w;
      w.x = (unsigned)pk[0] | ((unsigned)pk[1] << 16);
      w.y = (unsigned)pk[2] | ((unsigned)pk[3] << 16);
      *(uint2*)&Pw[l16*76 + kt*16 + quad*4] = w;
    }
    lsum += __shfl_xor(lsum, 16);
    lsum += __shfl_xor(lsum, 32);
    l_j = l_j*alpha + lsum;
    float ab[4];
    #pragma unroll
    for (int r=0;r<4;r++) ab[r] = __shfl(alpha, quad*4 + r, 64);
    #pragma unroll
    for (int d=0;d<4;d++)
      #pragma unroll
      for (int r=0;r<4;r++) oacc[d][r] *= ab[r];
    #pragma unroll
    for (int ks=0;ks<2;ks++){
      s16x8 pa = *(const s16x8*)&Pw[l16*76 + ks*32 + quad*8];
      #pragma unroll
      for (int dt=0;dt<4;dt++){
        s16x8 vv = *(const s16x8*)&Vs[(dt*16 + l16)*64 + (((ks*4+quad)^rx7)*8)];
        oacc[dt] = __builtin_amdgcn_mfma_f32_16x16x32_bf16(pa, vv, oacc[dt], 0,0,0);
      }
    }
  }
  int rowbase = qblk*64 + wave*16 + quad*4;
  if (SCATTER){
    float lb[4];
    #pragma unroll
    for (int r=0;r<4;r++) lb[r] = __shfl(l_j, quad*4 + r, 64);
    int b = bh >> 3, h = bh & 7;
    #pragma unroll
    for (int dt=0;dt<4;dt++){
      #pragma unroll
      for (int r=0;r<4;r++){
        int n = rowbase + r;
        ob[((size_t)(b*N_ + n))*DIM_ + h*D_ + dt*16 + l16] = f2bf(oacc[dt][r] / lb[r]);
      }
    }
  } else {
    size_t pb = ((size_t)(half*BH + bh)*M_ + rowbase)*D_;
    #pragma unroll
    for (int dt=0;dt<4;dt++){
      #pragma unroll
      for (int r=0;r<4;r++)
        up[pb + (size_t)r*D_ + dt*16 + l16] = oacc[dt][r];
    }
    if (lane < 16){
      size_t si = (size_t)(half*BH + bh)*M_ + qblk*64 + wave*16 + l16;
      mst[si] = m_j;
      lst[si] = l_j;
    }
  }
}

// ---------- combine 16 key-split partials -> u fp32 ----------
__global__ __launch_bounds__(256) void comb_k(const float* __restrict__ up,
    const float* __restrict__ mst, const float* __restrict__ lst,
    float* __restrict__ u){
  int idx = blockIdx.x*256 + threadIdx.x;
  int d = idx & 63; int row = (idx >> 6) & 255; int bh = idx >> 14;
  float m = -1e30f;
  float mv[16];
  #pragma unroll
  for (int hfs=0;hfs<16;hfs++){
    mv[hfs] = mst[(size_t)(hfs*BH + bh)*M_ + row];
    m = fmaxf(m, mv[hfs]);
  }
  float num = 0.f, den = 0.f;
  #pragma unroll
  for (int hfs=0;hfs<16;hfs++){
    float w = __expf(mv[hfs] - m);
    size_t ri = (size_t)(hfs*BH + bh)*M_ + row;
    den += lst[ri] * w;
    num += up[ri*D_ + d] * w;
  }
  u[idx] = num / den;
}

// ---------- w = z @ u (fp32) ----------
__global__ void zu_k(const float* __restrict__ z, const float* __restrict__ u,
                     float* __restrict__ w){
  int idx = blockIdx.x*256 + threadIdx.x;
  int d = idx & 63, i = (idx >> 6) & 255, bh = idx >> 14;
  const float* zr = z + ((size_t)bh*M_+i)*M_;
  const float* ub = u + (size_t)bh*M_*D_ + d;
  float acc = 0.f;
  for (int kk=0;kk<M_;kk++) acc += zr[kk]*ub[(size_t)kk*D_];
  w[idx] = acc;
}

// ---------- depthwise conv residual v3: 4n x 8d tile, weights in LDS ----------
__global__ __launch_bounds__(256) void conv3_k(const ushort_t* __restrict__ v,
    const float* __restrict__ cw, ushort_t* __restrict__ ob){
  int bh = blockIdx.y;
  int h = bh & 7, b = bh >> 3;
  int t = threadIdx.x;
  int d8 = (t & 7) * 8;
  int nloc = t >> 3;                       // 0..31
  int n0 = blockIdx.x * 128 + nloc * 4;
  __shared__ float wsm[33];
  if (t < 33) wsm[t] = cw[h*33 + t];
  __syncthreads();
  float acc[4][8];
  #pragma unroll
  for (int j=0;j<4;j++)
    #pragma unroll
    for (int dd=0;dd<8;dd++) acc[j][dd] = 0.f;
  const ushort_t* vbase = v + (size_t)bh*N_*D_;
  for (int r=0;r<36;r++){
    int nn = n0 - 16 + r;
    float vals[8];
    if (nn >= 0 && nn < N_){
      uint4 raw = *(const uint4*)&vbase[(size_t)nn*D_ + d8];
      const ushort_t* pr = (const ushort_t*)&raw;
      #pragma unroll
      for (int dd=0;dd<8;dd++) vals[dd] = bf2f(pr[dd]);
    } else {
      #pragma unroll
      for (int dd=0;dd<8;dd++) vals[dd] = 0.f;
    }
    #pragma unroll
    for (int j=0;j<4;j++){
      int tap = r - j;
      if (tap >= 0 && tap <= 32){
        float wj = wsm[tap];
        #pragma unroll
        for (int dd=0;dd<8;dd++) acc[j][dd] += wj * vals[dd];
      }
    }
  }
  #pragma unroll
  for (int j=0;j<4;j++){
    size_t oi = ((size_t)(b*N_ + n0 + j))*DIM_ + h*D_ + d8;
    uint4 cur = *(uint4*)&ob[oi];
    ushort_t* pc = (ushort_t*)&cur;
    #pragma unroll
    for (int dd=0;dd<8;dd++) pc[dd] = f2bf(bf2f(pc[dd]) + acc[j][dd]);
    *(uint4*)&ob[oi] = cur;
  }
}

extern "C" void kernel_launch(void* const* d_in, const int* in_sizes, int n_in,
                              void* d_out, int out_size, void* d_ws, size_t ws_size,
                              hipStream_t stream){
  (void)in_sizes; (void)n_in; (void)out_size; (void)ws_size;
  const float* x      = (const float*)d_in[0];
  const float* gamma  = (const float*)d_in[1];
  const float* beta   = (const float*)d_in[2];
  const float* w_qkv  = (const float*)d_in[3];
  const float* w_out  = (const float*)d_in[4];
  const float* b_out  = (const float*)d_in[5];
  const float* conv_w = (const float*)d_in[6];
  float* y = (float*)d_out;
  float* ws = (float*)d_ws;

  size_t off = 0;
  ushort_t* xnb   = (ushort_t*)(ws + off); off += 4194304;   // reused as az splits
  ushort_t* qb    = (ushort_t*)(ws + off); off += 4194304;
  ushort_t* kb    = (ushort_t*)(ws + off); off += 4194304;
  ushort_t* vb    = (ushort_t*)(ws + off); off += 4194304;
  ushort_t* vT    = (ushort_t*)(ws + off); off += 4194304;
  ushort_t* wqkvT = (ushort_t*)(ws + off); off += 393216;
  ushort_t* woutT = (ushort_t*)(ws + off); off += 131072;
  ushort_t* qlh   = (ushort_t*)(ws + off); off += 262144;
  ushort_t* qll   = (ushort_t*)(ws + off); off += 262144;
  ushort_t* klh   = (ushort_t*)(ws + off); off += 262144;
  ushort_t* kll   = (ushort_t*)(ws + off); off += 262144;
  ushort_t* wzT   = (ushort_t*)(ws + off); off += 262144;
  ushort_t* ob    = (ushort_t*)(ws + off); off += 4194304;
  ushort_t* a2h   = (ushort_t*)(ws + off); off += 1048576;
  ushort_t* a2l   = (ushort_t*)(ws + off); off += 1048576;
  ushort_t* z0h   = (ushort_t*)(ws + off); off += 1048576;
  ushort_t* z0l   = (ushort_t*)(ws + off); off += 1048576;
  ushort_t* z0Th  = (ushort_t*)(ws + off); off += 1048576;
  ushort_t* z0Tl  = (ushort_t*)(ws + off); off += 1048576;
  ushort_t* z1h   = (ushort_t*)(ws + off); off += 1048576;
  ushort_t* z1l   = (ushort_t*)(ws + off); off += 1048576;
  ushort_t* z1Th  = (ushort_t*)(ws + off); off += 1048576;
  ushort_t* z1Tl  = (ushort_t*)(ws + off); off += 1048576;
  ushort_t* t1Th  = (ushort_t*)(ws + off); off += 1048576;
  ushort_t* t1Tl  = (ushort_t*)(ws + off); off += 1048576;
  ushort_t* t2Th  = (ushort_t*)(ws + off); off += 1048576;
  ushort_t* t2Tl  = (ushort_t*)(ws + off); off += 1048576;
  float* ql  = ws + off;  off += 524288;
  float* kl  = ws + off;  off += 524288;
  float* a2f = ws + off;  off += 2097152;
  float* zf  = ws + off;  off += 2097152;
  float* u   = ws + off;  off += 524288;
  float* wz  = ws + off;  off += 524288;
  float* up  = ws + off;  off += 8388608;   // 16 key-splits x 32bh x 256 x 64
  float* mstat = ws + off; off += 131072;
  float* lstat = ws + off; off += 131072;
  float* cs  = ws + off;  off += 8192;
  ushort_t* azh  = xnb;
  ushort_t* azl  = xnb + 2097152;
  ushort_t* azTh = xnb + 2*2097152;
  ushort_t* azTl = xnb + 3*2097152;

  hipMemsetAsync(cs, 0, BH*M_*sizeof(float), stream);
  ln2_k<<<4096,256,0,stream>>>(x, gamma, beta, xnb);
  twbw_k<<<dim3(32,8,1),256,0,stream>>>(w_qkv, wqkvT, w_out, woutT);
  gemm_qkv_k<<<dim3(12,128),256,0,stream>>>(xnb, wqkvT, qb, kb, vb, vT);
  lmk_k<<<2048,256,0,stream>>>(qb, kb, ql, kl, qlh, qll, klh, kll);
  attn2m_k<<<dim3(8,32),128,0,stream>>>(qlh, qll, klh, kll, a2f, a2h, a2l, cs);
  initz4_k<<<dim3(4,4,32),256,0,stream>>>(a2f, cs, z0h, z0l, z0Th, z0Tl);

  ushort_t *zch = z0h, *zcl = z0l, *zcTh = z0Th, *zcTl = z0Tl;
  ushort_t *znh = z1h, *znl = z1l, *znTh = z1Th, *znTl = z1Tl;
  dim3 nsg(4,4,32);
  for (int it=0; it<6; it++){
    // az = a2@z
    ns3_k<false,true,true,false><<<nsg,256,0,stream>>>(a2h, a2l, zcTh, zcTl,
        0.f, -1.f, azh, azl, azTh, azTl, (float*)nullptr);
    // t1 = 7az - az@az
    ns3_k<true,false,true,false><<<nsg,256,0,stream>>>(azh, azl, azTh, azTl,
        7.f, 1.f, (ushort_t*)nullptr, (ushort_t*)nullptr, t1Th, t1Tl, (float*)nullptr);
    // t2 = 15az - az@t1
    ns3_k<true,false,true,false><<<nsg,256,0,stream>>>(azh, azl, t1Th, t1Tl,
        15.f, 1.f, (ushort_t*)nullptr, (ushort_t*)nullptr, t2Th, t2Tl, (float*)nullptr);
    // z' = 0.25*(13z - z@t2)
    if (it < 5)
      ns3_k<true,true,true,false><<<nsg,256,0,stream>>>(zch, zcl, t2Th, t2Tl,
          13.f, 0.25f, znh, znl, znTh, znTl, (float*)nullptr);
    else
      ns3_k<true,true,true,true><<<nsg,256,0,stream>>>(zch, zcl, t2Th, t2Tl,
          13.f, 0.25f, znh, znl, znTh, znTl, zf);
    { ushort_t* tp;
      tp=zch; zch=znh; znh=tp;  tp=zcl; zcl=znl; znl=tp;
      tp=zcTh; zcTh=znTh; znTh=tp;  tp=zcTl; zcTl=znTl; znTl=tp; }
  }

  attn8_k<4,false><<<dim3(4,16,32),256,0,stream>>>(qlh, kb, vT, M_, N_,
      up, mstat, lstat, (ushort_t*)nullptr);
  comb_k<<<2048,256,0,stream>>>(up, mstat, lstat, u);
  zu_k<<<2048,256,0,stream>>>(zf, u, wz);
  twb_k<<<dim3(1,4,32),256,0,stream>>>(wz, wzT, 256, 64);
  attn8_k<4,true><<<dim3(64,1,32),256,0,stream>>>(qb, klh, wzT, N_, M_,
      (float*)nullptr, (float*)nullptr, (float*)nullptr, ob);
  conv3_k<<<dim3(32,32),256,0,stream>>>(vb, conv_w, ob);
  final4_k<<<dim3(8,256),256,0,stream>>>(ob, woutT, b_out, x, y);
}

// Round 12
// 531.838 us; speedup vs baseline: 1.0182x; 1.0182x over previous
//
#include <hip/hip_runtime.h>
#include <math.h>

#define BH 32
#define N_ 4096
#define D_ 64
#define M_ 256
#define L_ 16
#define DIM_ 512
#define K3_ 1536

typedef __attribute__((ext_vector_type(4))) float f32x4;
typedef __attribute__((ext_vector_type(8))) short s16x8;
typedef unsigned short ushort_t;

__device__ inline ushort_t f2bf(float f){
  union{float f; unsigned u;} v; v.f = f;
  unsigned r = v.u + 0x7fffu + ((v.u >> 16) & 1u);
  return (ushort_t)(r >> 16);
}
__device__ inline float bf2f(ushort_t b){
  union{unsigned u; float f;} v; v.u = ((unsigned)b) << 16; return v.f;
}

// async global->LDS, 16B per lane. LDS dest wave-uniform base + lane*16
// (linear); global src addr is per-lane (carries the swizzle).
__device__ inline void gl_lds16(const ushort_t* g, ushort_t* l){
  __builtin_amdgcn_global_load_lds(
      (const __attribute__((address_space(1))) unsigned int*)g,
      (__attribute__((address_space(3))) unsigned int*)l, 16, 0, 0);
}

// XCD-aware bijective block remap (T1). Requires nwg % 8 == 0.
__device__ inline int xcd_swz_bid(){
  int bid = blockIdx.x + gridDim.x*(blockIdx.y + gridDim.y*blockIdx.z);
  int nwg = gridDim.x*gridDim.y*gridDim.z;
  int cpx = nwg >> 3;
  return (bid & 7)*cpx + (bid >> 3);
}

// ---------- reduction helpers ----------
__device__ inline float wave_sum_all(float v){
  #pragma unroll
  for (int o=1;o<64;o<<=1) v += __shfl_xor(v,o,64);
  return v;
}
__device__ inline float wave_max(float v){
  #pragma unroll
  for (int o=32;o;o>>=1) v = fmaxf(v,__shfl_down(v,o,64));
  return v;
}
__device__ inline float blk_max256(float v, float* sm){
  v = wave_max(v);
  int lane = threadIdx.x & 63, wid = threadIdx.x >> 6;
  if (lane==0) sm[wid]=v;
  __syncthreads();
  float r = fmaxf(fmaxf(sm[0],sm[1]),fmaxf(sm[2],sm[3]));
  __syncthreads();
  return r;
}

// ---------- 1. LayerNorm -> bf16: one wave per row, no barriers ----------
__global__ __launch_bounds__(256) void ln2_k(const float* __restrict__ x,
    const float* __restrict__ g, const float* __restrict__ bt, ushort_t* __restrict__ xn){
  int t = threadIdx.x, lane = t & 63, w = t >> 6;
  size_t row = (size_t)blockIdx.x*4 + w;
  const float* xr = x + row*DIM_;
  f32x4 a = *(const f32x4*)&xr[lane*8];
  f32x4 b = *(const f32x4*)&xr[lane*8+4];
  float s = a[0]+a[1]+a[2]+a[3]+b[0]+b[1]+b[2]+b[3];
  float mu = wave_sum_all(s) * (1.f/DIM_);
  float d[8];
  #pragma unroll
  for (int i=0;i<4;i++){ d[i] = a[i]-mu; d[i+4] = b[i]-mu; }
  float vs = 0.f;
  #pragma unroll
  for (int i=0;i<8;i++) vs += d[i]*d[i];
  float var = wave_sum_all(vs) * (1.f/DIM_);
  float rs = rsqrtf(var + 1e-5f);
  f32x4 g0 = *(const f32x4*)&g[lane*8], g1 = *(const f32x4*)&g[lane*8+4];
  f32x4 b0 = *(const f32x4*)&bt[lane*8], b1 = *(const f32x4*)&bt[lane*8+4];
  ushort_t tmp[8];
  #pragma unroll
  for (int i=0;i<4;i++){
    tmp[i]   = f2bf(d[i]*rs*g0[i]   + b0[i]);
    tmp[i+4] = f2bf(d[i+4]*rs*g1[i] + b1[i]);
  }
  *(uint4*)&xn[row*DIM_ + lane*8] = *(uint4*)tmp;
}

// ---------- merged weight transpose: bx<24 -> w_qkv (512x1536), else w_out (512x512) ----------
__global__ __launch_bounds__(256) void twbw_k(const float* __restrict__ wqkv,
    ushort_t* __restrict__ wqkvT, const float* __restrict__ wout,
    ushort_t* __restrict__ woutT){
  __shared__ ushort_t tile[64][66];
  const float* src; ushort_t* dst; int R = 512, C;
  int bx = blockIdx.x;
  if (bx < 24){ src = wqkv; dst = wqkvT; C = 1536; }
  else        { src = wout; dst = woutT; C = 512; bx -= 24; }
  int r0 = blockIdx.y*64, c0 = bx*64;
  int t = threadIdx.x, c = t & 63, r4 = t >> 6;
  #pragma unroll
  for (int i=0;i<16;i++){
    int rr = r4 + i*4;
    tile[c][rr] = f2bf(src[(size_t)(r0+rr)*C + (c0+c)]);
  }
  __syncthreads();
  #pragma unroll
  for (int i=0;i<16;i++){
    int cc = r4 + i*4;
    dst[(size_t)(c0+cc)*R + (r0 + c)] = tile[cc][c];
  }
}
// ---------- transpose fp32 [R][C] -> bf16 [C][R], batched via z ----------
__global__ __launch_bounds__(256) void twb_k(const float* __restrict__ src,
    ushort_t* __restrict__ dst, int R, int C){
  __shared__ ushort_t tile[64][66];
  size_t boff = (size_t)blockIdx.z * R * C;
  int r0 = blockIdx.y*64, c0 = blockIdx.x*64;
  int t = threadIdx.x, c = t & 63, r4 = t >> 6;
  #pragma unroll
  for (int i=0;i<16;i++){
    int rr = r4 + i*4;
    tile[c][rr] = f2bf(src[boff + (size_t)(r0+rr)*C + (c0+c)]);
  }
  __syncthreads();
  #pragma unroll
  for (int i=0;i<16;i++){
    int cc = r4 + i*4;
    dst[boff + (size_t)(c0+cc)*R + (r0 + c)] = tile[cc][c];
  }
}
// ---------- transpose bf16 [R][C] -> bf16 [C][R], batched ----------
__global__ __launch_bounds__(256) void tbb_k(const ushort_t* __restrict__ src,
    ushort_t* __restrict__ dst, int R, int C){
  __shared__ ushort_t tile[64][66];
  size_t boff = (size_t)blockIdx.z * R * C;
  int r0 = blockIdx.y*64, c0 = blockIdx.x*64;
  int t = threadIdx.x, c = t & 63, r4 = t >> 6;
  #pragma unroll
  for (int i=0;i<16;i++){
    int rr = r4 + i*4;
    tile[c][rr] = src[boff + (size_t)(r0+rr)*C + (c0+c)];
  }
  __syncthreads();
  #pragma unroll
  for (int i=0;i<16;i++){
    int cc = r4 + i*4;
    dst[boff + (size_t)(c0+cc)*R + (r0 + c)] = tile[cc][c];
  }
}

// ---------- 2. QKV GEMM bf16 MFMA (XCD-swizzled, global_load_lds staging) ----------
__global__ __launch_bounds__(256) void gemm_qkv_k(const ushort_t* __restrict__ A,
    const ushort_t* __restrict__ Bt, ushort_t* __restrict__ qb, ushort_t* __restrict__ kb,
    ushort_t* __restrict__ vb){
  __shared__ __align__(16) ushort_t As[128*64];
  __shared__ __align__(16) ushort_t Bs[128*64];
  int t = threadIdx.x;
  int lane = t & 63, wave = t >> 6;
  int l16 = lane & 15, quad = lane >> 4;
  int wm = (wave & 1) * 64, wn = (wave >> 1) * 64;
  int swz = xcd_swz_bid();
  int bx = swz % gridDim.x, by = swz / gridDim.x;
  int row0 = by * 128, col0 = bx * 128;
  f32x4 acc[4][4];
  #pragma unroll
  for (int i=0;i<4;i++)
    #pragma unroll
    for (int j=0;j<4;j++) acc[i][j] = (f32x4){0.f,0.f,0.f,0.f};
  int lr = lane >> 3, lc = lane & 7;
  int scol = (lc ^ lr) * 8;
  int rx7 = l16 & 7;
  for (int k0=0;k0<DIM_;k0+=64){
    __syncthreads();
    #pragma unroll
    for (int p=0;p<4;p++){
      int r = wave*8 + p*32;
      gl_lds16(&A [(size_t)(row0+r+lr)*DIM_ + k0 + scol], &As[(size_t)r*64]);
      gl_lds16(&Bt[(size_t)(col0+r+lr)*DIM_ + k0 + scol], &Bs[(size_t)r*64]);
    }
    __syncthreads();
    s16x8 af[4][2], bf[4][2];
    #pragma unroll
    for (int mt=0;mt<4;mt++)
      #pragma unroll
      for (int kk=0;kk<2;kk++)
        af[mt][kk] = *(const s16x8*)&As[(wm + mt*16 + l16)*64 + (((kk*4+quad)^rx7)*8)];
    #pragma unroll
    for (int nt=0;nt<4;nt++)
      #pragma unroll
      for (int kk=0;kk<2;kk++)
        bf[nt][kk] = *(const s16x8*)&Bs[(wn + nt*16 + l16)*64 + (((kk*4+quad)^rx7)*8)];
    #pragma unroll
    for (int mt=0;mt<4;mt++)
      #pragma unroll
      for (int nt=0;nt<4;nt++)
        #pragma unroll
        for (int kk=0;kk<2;kk++)
          acc[mt][nt] = __builtin_amdgcn_mfma_f32_16x16x32_bf16(af[mt][kk], bf[nt][kk], acc[mt][nt], 0,0,0);
  }
  #pragma unroll
  for (int mt=0;mt<4;mt++){
    #pragma unroll
    for (int nt=0;nt<4;nt++){
      #pragma unroll
      for (int reg=0;reg<4;reg++){
        int row = row0 + wm + mt*16 + quad*4 + reg;
        int col = col0 + wn + nt*16 + l16;
        float val = acc[mt][nt][reg];
        int b = row >> 12, n = row & 4095;
        int which = col >> 9, rem = col & 511;
        int h = rem >> 6, d = rem & 63;
        size_t dst = ((size_t)((b<<3)+h)*N_ + n)*D_ + d;
        if (which==0)      qb[dst] = f2bf(val*0.125f);
        else if (which==1) kb[dst] = f2bf(val);
        else               vb[dst] = f2bf(val);
      }
    }
  }
}

// ---------- final GEMM v3: 128x64 tiles, global_load_lds staging ----------
__global__ __launch_bounds__(256) void final3_k(const ushort_t* __restrict__ A,
    const ushort_t* __restrict__ Bt, const float* __restrict__ bo,
    const float* __restrict__ x, float* __restrict__ y){
  __shared__ __align__(16) ushort_t As[128*64];
  __shared__ __align__(16) ushort_t Bs[64*64];
  int t = threadIdx.x;
  int lane = t & 63, wave = t >> 6;
  int l16 = lane & 15, quad = lane >> 4;
  int wm = wave * 32;
  int swz = xcd_swz_bid();
  int bx = swz % gridDim.x, by = swz / gridDim.x;
  int row0 = by * 128, col0 = bx * 64;
  f32x4 acc[2][4];
  #pragma unroll
  for (int i=0;i<2;i++)
    #pragma unroll
    for (int j=0;j<4;j++) acc[i][j] = (f32x4){0.f,0.f,0.f,0.f};
  int lr = lane >> 3, lc = lane & 7;
  int scol = (lc ^ lr) * 8;
  int rx7 = l16 & 7;
  for (int k0=0;k0<DIM_;k0+=64){
    __syncthreads();
    #pragma unroll
    for (int p=0;p<4;p++){
      int r = wave*8 + p*32;
      gl_lds16(&A[(size_t)(row0+r+lr)*DIM_ + k0 + scol], &As[(size_t)r*64]);
    }
    #pragma unroll
    for (int p=0;p<2;p++){
      int r = wave*8 + p*32;
      gl_lds16(&Bt[(size_t)(col0+r+lr)*DIM_ + k0 + scol], &Bs[(size_t)r*64]);
    }
    __syncthreads();
    s16x8 af[2][2], bf[4][2];
    #pragma unroll
    for (int mt=0;mt<2;mt++)
      #pragma unroll
      for (int kk=0;kk<2;kk++)
        af[mt][kk] = *(const s16x8*)&As[(wm + mt*16 + l16)*64 + (((kk*4+quad)^rx7)*8)];
    #pragma unroll
    for (int nt=0;nt<4;nt++)
      #pragma unroll
      for (int kk=0;kk<2;kk++)
        bf[nt][kk] = *(const s16x8*)&Bs[(nt*16 + l16)*64 + (((kk*4+quad)^rx7)*8)];
    #pragma unroll
    for (int mt=0;mt<2;mt++)
      #pragma unroll
      for (int nt=0;nt<4;nt++)
        #pragma unroll
        for (int kk=0;kk<2;kk++)
          acc[mt][nt] = __builtin_amdgcn_mfma_f32_16x16x32_bf16(af[mt][kk], bf[nt][kk], acc[mt][nt], 0,0,0);
  }
  #pragma unroll
  for (int mt=0;mt<2;mt++){
    #pragma unroll
    for (int nt=0;nt<4;nt++){
      int col = col0 + nt*16 + l16;
      #pragma unroll
      for (int reg=0;reg<4;reg++){
        int row = row0 + wm + mt*16 + quad*4 + reg;
        size_t o = (size_t)row*DIM_ + col;
        y[o] = acc[mt][nt][reg] + bo[col] + x[o];
      }
    }
  }
}

// ---------- 3. landmark means (fp32 + bf16 h/l splits) ----------
__global__ void lmk_k(const ushort_t* __restrict__ q, const ushort_t* __restrict__ k,
                      float* __restrict__ ql, float* __restrict__ kl,
                      ushort_t* __restrict__ qlh, ushort_t* __restrict__ qll,
                      ushort_t* __restrict__ klh, ushort_t* __restrict__ kll){
  int idx = blockIdx.x*256 + threadIdx.x;
  int d = idx & 63, i = (idx >> 6) & 255, bh = idx >> 14;
  size_t base = ((size_t)bh*N_ + i*L_)*D_ + d;
  float sq=0.f, sk=0.f;
  #pragma unroll
  for (int tt=0;tt<L_;tt++){ sq += bf2f(q[base + (size_t)tt*D_]); sk += bf2f(k[base + (size_t)tt*D_]); }
  sq *= (1.f/L_); sk *= (1.f/L_);
  ql[idx] = sq; kl[idx] = sk;
  ushort_t qh = f2bf(sq), kh = f2bf(sk);
  qlh[idx] = qh; qll[idx] = f2bf(sq - bf2f(qh));
  klh[idx] = kh; kll[idx] = f2bf(sk - bf2f(kh));
}

// ---------- 4. attn2 via split-bf16 MFMA, fused col sums ----------
__global__ __launch_bounds__(256) void attn2m_k(
    const ushort_t* __restrict__ qlh, const ushort_t* __restrict__ qll,
    const ushort_t* __restrict__ klh, const ushort_t* __restrict__ kll,
    float* __restrict__ a2f, ushort_t* __restrict__ a2h, ushort_t* __restrict__ a2l,
    float* __restrict__ cs){
  int bh = blockIdx.y;
  int t = threadIdx.x, wave = t >> 6, lane = t & 63;
  int l16 = lane & 15, quad = lane >> 4;
  size_t mo = (size_t)bh*M_*M_;
  int rowtile = blockIdx.x*32 + wave*16;
  size_t qbase = ((size_t)bh*M_ + rowtile + l16)*D_;
  s16x8 qh0 = *(const s16x8*)&qlh[qbase + quad*8];
  s16x8 qh1 = *(const s16x8*)&qlh[qbase + 32 + quad*8];
  s16x8 qv0 = *(const s16x8*)&qll[qbase + quad*8];
  s16x8 qv1 = *(const s16x8*)&qll[qbase + 32 + quad*8];
  f32x4 s[16];
  #pragma unroll
  for (int kt=0;kt<16;kt++){
    size_t kb = ((size_t)bh*M_ + kt*16 + l16)*D_;
    s16x8 kh0 = *(const s16x8*)&klh[kb + quad*8];
    s16x8 kh1 = *(const s16x8*)&klh[kb + 32 + quad*8];
    s16x8 kv0 = *(const s16x8*)&kll[kb + quad*8];
    s16x8 kv1 = *(const s16x8*)&kll[kb + 32 + quad*8];
    f32x4 z = (f32x4){0.f,0.f,0.f,0.f};
    z = __builtin_amdgcn_mfma_f32_16x16x32_bf16(qh0, kh0, z, 0,0,0);
    z = __builtin_amdgcn_mfma_f32_16x16x32_bf16(qh1, kh1, z, 0,0,0);
    z = __builtin_amdgcn_mfma_f32_16x16x32_bf16(qh0, kv0, z, 0,0,0);
    z = __builtin_amdgcn_mfma_f32_16x16x32_bf16(qh1, kv1, z, 0,0,0);
    z = __builtin_amdgcn_mfma_f32_16x16x32_bf16(qv0, kh0, z, 0,0,0);
    z = __builtin_amdgcn_mfma_f32_16x16x32_bf16(qv1, kh1, z, 0,0,0);
    s[kt] = z;
  }
  float mx[4], inv[4];
  #pragma unroll
  for (int r=0;r<4;r++){
    float m = s[0][r];
    #pragma unroll
    for (int kt=1;kt<16;kt++) m = fmaxf(m, s[kt][r]);
    m = fmaxf(m, __shfl_xor(m, 1));
    m = fmaxf(m, __shfl_xor(m, 2));
    m = fmaxf(m, __shfl_xor(m, 4));
    m = fmaxf(m, __shfl_xor(m, 8));
    mx[r] = m;
  }
  float lsum[4] = {0.f,0.f,0.f,0.f};
  #pragma unroll
  for (int kt=0;kt<16;kt++){
    #pragma unroll
    for (int r=0;r<4;r++){
      float e = expf(s[kt][r] - mx[r]);
      s[kt][r] = e;
      lsum[r] += e;
    }
  }
  #pragma unroll
  for (int r=0;r<4;r++){
    float ls = lsum[r];
    ls += __shfl_xor(ls, 1);
    ls += __shfl_xor(ls, 2);
    ls += __shfl_xor(ls, 4);
    ls += __shfl_xor(ls, 8);
    inv[r] = 1.f/ls;
  }
  #pragma unroll
  for (int kt=0;kt<16;kt++){
    int c = kt*16 + l16;
    float csum = 0.f;
    #pragma unroll
    for (int r=0;r<4;r++){
      float p = s[kt][r]*inv[r];
      csum += p;
      size_t oi = mo + (size_t)(rowtile + quad*4 + r)*M_ + c;
      a2f[oi] = p;
      ushort_t hh = f2bf(p);
      a2h[oi] = hh;
      a2l[oi] = f2bf(p - bf2f(hh));
    }
    csum += __shfl_xor(csum, 16);
    csum += __shfl_xor(csum, 32);
    if (lane < 16) atomicAdd(&cs[(size_t)bh*M_ + c], csum);
  }
}

// ---------- initz v4: fused scal = 1/max(cs) (row sums are exactly 1) ----------
__global__ __launch_bounds__(256) void initz4_k(const float* __restrict__ a2,
    const float* __restrict__ cs,
    ushort_t* __restrict__ zh, ushort_t* __restrict__ zl,
    ushort_t* __restrict__ zTh, ushort_t* __restrict__ zTl){
  __shared__ float tile[64][65];
  __shared__ float sm[4];
  float cm = -1e30f;
  for (int i=threadIdx.x; i<BH*M_; i+=256) cm = fmaxf(cm, cs[i]);
  cm = blk_max256(cm, sm);
  float s = 1.f/cm;
  int bh = blockIdx.z;
  size_t mo = (size_t)bh*M_*M_;
  int r0 = blockIdx.y*64, c0 = blockIdx.x*64;
  int t = threadIdx.x, c = t & 63, r4 = t >> 6;
  #pragma unroll
  for (int i=0;i<16;i++){
    int rr = r4 + i*4;
    float v = a2[mo + (size_t)(r0+rr)*M_ + c0 + c] * s;
    tile[rr][c] = v;
    ushort_t hh = f2bf(v);
    size_t oi = mo + (size_t)(r0+rr)*M_ + c0 + c;
    zTh[oi] = hh;
    zTl[oi] = f2bf(v - bf2f(hh));
  }
  __syncthreads();
  #pragma unroll
  for (int i=0;i<16;i++){
    int zr = r4 + i*4;
    float v = tile[c][zr];
    size_t oi = mo + (size_t)(c0+zr)*M_ + r0 + c;
    ushort_t hh = f2bf(v);
    zh[oi] = hh;
    zl[oi] = f2bf(v - bf2f(hh));
  }
}

// ---------- Newton-Schulz GEMM: 64x64 tiles, global_load_lds staging ----------
template<bool HASCOEF, bool WN, bool WT, bool WF>
__global__ __launch_bounds__(256) void ns3_k(
    const ushort_t* __restrict__ Ah, const ushort_t* __restrict__ Al,
    const ushort_t* __restrict__ BTh, const ushort_t* __restrict__ BTl,
    float coef, float scale,
    ushort_t* __restrict__ Ch, ushort_t* __restrict__ Cl,
    ushort_t* __restrict__ CTh, ushort_t* __restrict__ CTl,
    float* __restrict__ Cf){
  __shared__ __align__(16) ushort_t Ahs[64*64];
  __shared__ __align__(16) ushort_t Als[64*64];
  __shared__ __align__(16) ushort_t Bhs[64*64];
  __shared__ __align__(16) ushort_t Bls[64*64];
  int swz = xcd_swz_bid();
  int bx = swz % gridDim.x; int rem = swz / gridDim.x;
  int by = rem % gridDim.y; int batch = rem / gridDim.y;
  size_t mo = (size_t)batch*M_*M_;
  int row0 = by*64, col0 = bx*64;
  int t = threadIdx.x, lane = t & 63, wave = t >> 6;
  int l16 = lane & 15, quad = lane >> 4;
  f32x4 acc[4];
  #pragma unroll
  for (int j=0;j<4;j++) acc[j] = (f32x4){0.f,0.f,0.f,0.f};
  int lr = lane >> 3, lc = lane & 7;
  int scol = (lc ^ lr) * 8;
  int rx7 = l16 & 7;
  for (int k0=0;k0<M_;k0+=64){
    __syncthreads();
    #pragma unroll
    for (int p=0;p<2;p++){
      int r = wave*8 + p*32;
      gl_lds16(&Ah [mo + (size_t)(row0+r+lr)*M_ + k0 + scol], &Ahs[(size_t)r*64]);
      gl_lds16(&Al [mo + (size_t)(row0+r+lr)*M_ + k0 + scol], &Als[(size_t)r*64]);
      gl_lds16(&BTh[mo + (size_t)(col0+r+lr)*M_ + k0 + scol], &Bhs[(size_t)r*64]);
      gl_lds16(&BTl[mo + (size_t)(col0+r+lr)*M_ + k0 + scol], &Bls[(size_t)r*64]);
    }
    __syncthreads();
    s16x8 fah[2], fal[2];
    #pragma unroll
    for (int kk=0;kk<2;kk++){
      fah[kk] = *(const s16x8*)&Ahs[(wave*16 + l16)*64 + (((kk*4+quad)^rx7)*8)];
      fal[kk] = *(const s16x8*)&Als[(wave*16 + l16)*64 + (((kk*4+quad)^rx7)*8)];
    }
    #pragma unroll
    for (int nt=0;nt<4;nt++){
      #pragma unroll
      for (int kk=0;kk<2;kk++){
        s16x8 fbh = *(const s16x8*)&Bhs[(nt*16 + l16)*64 + (((kk*4+quad)^rx7)*8)];
        s16x8 fbl = *(const s16x8*)&Bls[(nt*16 + l16)*64 + (((kk*4+quad)^rx7)*8)];
        acc[nt] = __builtin_amdgcn_mfma_f32_16x16x32_bf16(fah[kk], fbh, acc[nt], 0,0,0);
        acc[nt] = __builtin_amdgcn_mfma_f32_16x16x32_bf16(fah[kk], fbl, acc[nt], 0,0,0);
        acc[nt] = __builtin_amdgcn_mfma_f32_16x16x32_bf16(fal[kk], fbh, acc[nt], 0,0,0);
      }
    }
  }
  int rbase = row0 + wave*16 + quad*4;
  #pragma unroll
  for (int nt=0;nt<4;nt++){
    int c = col0 + nt*16 + l16;
    ushort_t th[4], tl[4];
    #pragma unroll
    for (int reg=0;reg<4;reg++){
      float a = acc[nt][reg];
      float base = 0.f;
      if (HASCOEF){
        size_t ai = mo + (size_t)(rbase+reg)*M_ + c;
        base = coef*(bf2f(Ah[ai]) + bf2f(Al[ai]));
      }
      float v = scale*(base - a);
      if (WF) Cf[mo + (size_t)(rbase+reg)*M_ + c] = v;
      ushort_t hh = f2bf(v);
      ushort_t ll = f2bf(v - bf2f(hh));
      if (WN){
        Ch[mo + (size_t)(rbase+reg)*M_ + c] = hh;
        Cl[mo + (size_t)(rbase+reg)*M_ + c] = ll;
      }
      th[reg] = hh; tl[reg] = ll;
    }
    if (WT){
      uint2 vh; vh.x = (unsigned)th[0] | ((unsigned)th[1]<<16); vh.y = (unsigned)th[2] | ((unsigned)th[3]<<16);
      uint2 vl; vl.x = (unsigned)tl[0] | ((unsigned)tl[1]<<16); vl.y = (unsigned)tl[2] | ((unsigned)tl[3]<<16);
      *(uint2*)&CTh[mo + (size_t)c*M_ + rbase] = vh;
      *(uint2*)&CTl[mo + (size_t)c*M_ + rbase] = vl;
    }
  }
}

// ---------- flash attention v9: transposed-QK + gl_lds K/V staging ----------
// SCATTER variant fuses the depthwise conv residual: after the K/V loop the
// KV LDS buffer (dead) is reused to stage v[n0-16..n0+79][0..63] (stride 72),
// each thread adds its 4x4 conv taps before the ob store. conv3_k removed.
template<int ITERS, bool SCATTER>
__global__ __launch_bounds__(256) void attn9_k(const ushort_t* __restrict__ Q,
    const ushort_t* __restrict__ K, const ushort_t* __restrict__ VT,
    int nq, int nk,
    float* __restrict__ up, float* __restrict__ mst, float* __restrict__ lst,
    ushort_t* __restrict__ ob,
    const ushort_t* __restrict__ vsrc, const float* __restrict__ cw){
  __shared__ __align__(16) ushort_t KV[2*64*64];   // Ks | Vs; conv window view
  __shared__ __align__(16) ushort_t Pb[4*16*76];
  __shared__ float wsm[33];
  ushort_t* Ks = KV;
  ushort_t* Vs = KV + 64*64;
  int swz = xcd_swz_bid();
  int qblk = swz % gridDim.x; int rem0 = swz / gridDim.x;
  int half = rem0 % gridDim.y; int bh = rem0 / gridDim.y;
  int key0 = half * (ITERS*64);
  int t = threadIdx.x, wave = t >> 6, lane = t & 63;
  int l16 = lane & 15, quad = lane >> 4;
  if (SCATTER && t < 33) wsm[t] = cw[(bh & 7)*33 + t];
  size_t qbase = ((size_t)bh*nq + qblk*64 + wave*16 + l16)*D_;
  s16x8 qa0 = *(const s16x8*)&Q[qbase + quad*8];
  s16x8 qa1 = *(const s16x8*)&Q[qbase + 32 + quad*8];
  const ushort_t* Kb = K + (size_t)bh*nk*D_;
  const ushort_t* Vb = VT + (size_t)bh*D_*nk;
  ushort_t* Pw = &Pb[wave*16*76];
  int lr = lane >> 3, lc = lane & 7;
  int scol = (lc ^ lr) * 8;
  int rx7 = l16 & 7;
  float m_j = -1e30f, l_j = 0.f;
  f32x4 oacc[4];
  #pragma unroll
  for (int d=0;d<4;d++) oacc[d] = (f32x4){0.f,0.f,0.f,0.f};
  for (int it=0; it<ITERS; it++){
    int j0 = key0 + it*64;
    __syncthreads();
    #pragma unroll
    for (int p=0;p<2;p++){
      int r = wave*8 + p*32;
      gl_lds16(&Kb[(size_t)(j0+r+lr)*D_ + scol], &Ks[(size_t)r*64]);
      gl_lds16(&Vb[(size_t)(r+lr)*nk + j0 + scol], &Vs[(size_t)r*64]);
    }
    __syncthreads();
    f32x4 st[4];
    #pragma unroll
    for (int kt=0;kt<4;kt++){
      s16x8 b0 = *(const s16x8*)&Ks[(kt*16 + l16)*64 + ((quad^rx7)*8)];
      s16x8 b1 = *(const s16x8*)&Ks[(kt*16 + l16)*64 + (((4+quad)^rx7)*8)];
      f32x4 z = (f32x4){0.f,0.f,0.f,0.f};
      z = __builtin_amdgcn_mfma_f32_16x16x32_bf16(b0, qa0, z, 0,0,0);
      z = __builtin_amdgcn_mfma_f32_16x16x32_bf16(b1, qa1, z, 0,0,0);
      st[kt] = z;
    }
    float mx = st[0][0];
    #pragma unroll
    for (int kt=0;kt<4;kt++)
      #pragma unroll
      for (int r=0;r<4;r++) mx = fmaxf(mx, st[kt][r]);
    mx = fmaxf(mx, __shfl_xor(mx, 16));
    mx = fmaxf(mx, __shfl_xor(mx, 32));
    float mn = fmaxf(m_j, mx);
    float alpha = __expf(m_j - mn);
    m_j = mn;
    float lsum = 0.f;
    #pragma unroll
    for (int kt=0;kt<4;kt++){
      ushort_t pk[4];
      #pragma unroll
      for (int r=0;r<4;r++){
        float p = __expf(st[kt][r] - mn);
        lsum += p;
        pk[r] = f2bf(p);
      }
      uint2 w;
      w.x = (unsigned)pk[0] | ((unsigned)pk[1] << 16);
      w.y = (unsigned)pk[2] | ((unsigned)pk[3] << 16);
      *(uint2*)&Pw[l16*76 + kt*16 + quad*4] = w;
    }
    lsum += __shfl_xor(lsum, 16);
    lsum += __shfl_xor(lsum, 32);
    l_j = l_j*alpha + lsum;
    float ab[4];
    #pragma unroll
    for (int r=0;r<4;r++) ab[r] = __shfl(alpha, quad*4 + r, 64);
    #pragma unroll
    for (int d=0;d<4;d++)
      #pragma unroll
      for (int r=0;r<4;r++) oacc[d][r] *= ab[r];
    #pragma unroll
    for (int ks=0;ks<2;ks++){
      s16x8 pa = *(const s16x8*)&Pw[l16*76 + ks*32 + quad*8];
      #pragma unroll
      for (int dt=0;dt<4;dt++){
        s16x8 vv = *(const s16x8*)&Vs[(dt*16 + l16)*64 + (((ks*4+quad)^rx7)*8)];
        oacc[dt] = __builtin_amdgcn_mfma_f32_16x16x32_bf16(pa, vv, oacc[dt], 0,0,0);
      }
    }
  }
  int rowbase = qblk*64 + wave*16 + quad*4;
  if (SCATTER){
    // stage conv window v[n0-16 .. n0+79][0..63] into KV (stride 72, 16B-aligned rows)
    __syncthreads();
    const ushort_t* vbb = vsrc + (size_t)bh*N_*D_;
    int n0 = qblk*64;
    #pragma unroll
    for (int p=0;p<3;p++){
      int s = t + p*256;
      int row = s >> 3, dcol = (s & 7)*8;
      int nn = n0 - 16 + row;
      uint4 val;
      if (nn >= 0 && nn < N_) val = *(const uint4*)&vbb[(size_t)nn*D_ + dcol];
      else { val.x = 0; val.y = 0; val.z = 0; val.w = 0; }
      *(uint4*)&KV[row*72 + dcol] = val;
    }
    __syncthreads();
    float cacc[4][4];
    #pragma unroll
    for (int dt=0;dt<4;dt++)
      #pragma unroll
      for (int r=0;r<4;r++) cacc[dt][r] = 0.f;
    int wbase = wave*16 + quad*4;   // window row for r=0, tap j=0
    for (int rr=0; rr<36; rr++){
      float vals[4];
      #pragma unroll
      for (int dt=0;dt<4;dt++) vals[dt] = bf2f(KV[(wbase+rr)*72 + dt*16 + l16]);
      #pragma unroll
      for (int r=0;r<4;r++){
        int tap = rr - r;
        if (tap >= 0 && tap <= 32){
          float wj = wsm[tap];
          #pragma unroll
          for (int dt=0;dt<4;dt++) cacc[dt][r] += wj * vals[dt];
        }
      }
    }
    float lb[4];
    #pragma unroll
    for (int r=0;r<4;r++) lb[r] = __shfl(l_j, quad*4 + r, 64);
    int b = bh >> 3, h = bh & 7;
    #pragma unroll
    for (int dt=0;dt<4;dt++){
      #pragma unroll
      for (int r=0;r<4;r++){
        int n = rowbase + r;
        ob[((size_t)(b*N_ + n))*DIM_ + h*D_ + dt*16 + l16] =
            f2bf(oacc[dt][r] / lb[r] + cacc[dt][r]);
      }
    }
  } else {
    size_t pb = ((size_t)(half*BH + bh)*M_ + rowbase)*D_;
    #pragma unroll
    for (int dt=0;dt<4;dt++){
      #pragma unroll
      for (int r=0;r<4;r++)
        up[pb + (size_t)r*D_ + dt*16 + l16] = oacc[dt][r];
    }
    if (lane < 16){
      size_t si = (size_t)(half*BH + bh)*M_ + qblk*64 + wave*16 + l16;
      mst[si] = m_j;
      lst[si] = l_j;
    }
  }
}

// ---------- combine 16 key-split partials -> u fp32 ----------
__global__ __launch_bounds__(256) void comb_k(const float* __restrict__ up,
    const float* __restrict__ mst, const float* __restrict__ lst,
    float* __restrict__ u){
  int idx = blockIdx.x*256 + threadIdx.x;
  int d = idx & 63; int row = (idx >> 6) & 255; int bh = idx >> 14;
  float m = -1e30f;
  float mv[16];
  #pragma unroll
  for (int hfs=0;hfs<16;hfs++){
    mv[hfs] = mst[(size_t)(hfs*BH + bh)*M_ + row];
    m = fmaxf(m, mv[hfs]);
  }
  float num = 0.f, den = 0.f;
  #pragma unroll
  for (int hfs=0;hfs<16;hfs++){
    float w = __expf(mv[hfs] - m);
    size_t ri = (size_t)(hfs*BH + bh)*M_ + row;
    den += lst[ri] * w;
    num += up[ri*D_ + d] * w;
  }
  u[idx] = num / den;
}

// ---------- w = z @ u (fp32) ----------
__global__ void zu_k(const float* __restrict__ z, const float* __restrict__ u,
                     float* __restrict__ w){
  int idx = blockIdx.x*256 + threadIdx.x;
  int d = idx & 63, i = (idx >> 6) & 255, bh = idx >> 14;
  const float* zr = z + ((size_t)bh*M_+i)*M_;
  const float* ub = u + (size_t)bh*M_*D_ + d;
  float acc = 0.f;
  for (int kk=0;kk<M_;kk++) acc += zr[kk]*ub[(size_t)kk*D_];
  w[idx] = acc;
}

extern "C" void kernel_launch(void* const* d_in, const int* in_sizes, int n_in,
                              void* d_out, int out_size, void* d_ws, size_t ws_size,
                              hipStream_t stream){
  (void)in_sizes; (void)n_in; (void)out_size; (void)ws_size;
  const float* x      = (const float*)d_in[0];
  const float* gamma  = (const float*)d_in[1];
  const float* beta   = (const float*)d_in[2];
  const float* w_qkv  = (const float*)d_in[3];
  const float* w_out  = (const float*)d_in[4];
  const float* b_out  = (const float*)d_in[5];
  const float* conv_w = (const float*)d_in[6];
  float* y = (float*)d_out;
  float* ws = (float*)d_ws;

  size_t off = 0;
  ushort_t* xnb   = (ushort_t*)(ws + off); off += 4194304;   // reused as az splits
  ushort_t* qb    = (ushort_t*)(ws + off); off += 4194304;
  ushort_t* kb    = (ushort_t*)(ws + off); off += 4194304;
  ushort_t* vb    = (ushort_t*)(ws + off); off += 4194304;
  ushort_t* vT    = (ushort_t*)(ws + off); off += 4194304;
  ushort_t* wqkvT = (ushort_t*)(ws + off); off += 393216;
  ushort_t* woutT = (ushort_t*)(ws + off); off += 131072;
  ushort_t* qlh   = (ushort_t*)(ws + off); off += 262144;
  ushort_t* qll   = (ushort_t*)(ws + off); off += 262144;
  ushort_t* klh   = (ushort_t*)(ws + off); off += 262144;
  ushort_t* kll   = (ushort_t*)(ws + off); off += 262144;
  ushort_t* wzT   = (ushort_t*)(ws + off); off += 262144;
  ushort_t* ob    = (ushort_t*)(ws + off); off += 4194304;
  ushort_t* a2h   = (ushort_t*)(ws + off); off += 1048576;
  ushort_t* a2l   = (ushort_t*)(ws + off); off += 1048576;
  ushort_t* z0h   = (ushort_t*)(ws + off); off += 1048576;
  ushort_t* z0l   = (ushort_t*)(ws + off); off += 1048576;
  ushort_t* z0Th  = (ushort_t*)(ws + off); off += 1048576;
  ushort_t* z0Tl  = (ushort_t*)(ws + off); off += 1048576;
  ushort_t* z1h   = (ushort_t*)(ws + off); off += 1048576;
  ushort_t* z1l   = (ushort_t*)(ws + off); off += 1048576;
  ushort_t* z1Th  = (ushort_t*)(ws + off); off += 1048576;
  ushort_t* z1Tl  = (ushort_t*)(ws + off); off += 1048576;
  ushort_t* t1Th  = (ushort_t*)(ws + off); off += 1048576;
  ushort_t* t1Tl  = (ushort_t*)(ws + off); off += 1048576;
  ushort_t* t2Th  = (ushort_t*)(ws + off); off += 1048576;
  ushort_t* t2Tl  = (ushort_t*)(ws + off); off += 1048576;
  float* ql  = ws + off;  off += 524288;
  float* kl  = ws + off;  off += 524288;
  float* a2f = ws + off;  off += 2097152;
  float* zf  = ws + off;  off += 2097152;
  float* u   = ws + off;  off += 524288;
  float* wz  = ws + off;  off += 524288;
  float* up  = ws + off;  off += 8388608;   // 16 key-splits x 32bh x 256 x 64
  float* mstat = ws + off; off += 131072;
  float* lstat = ws + off; off += 131072;
  float* cs  = ws + off;  off += 8192;
  ushort_t* azh  = xnb;
  ushort_t* azl  = xnb + 2097152;
  ushort_t* azTh = xnb + 2*2097152;
  ushort_t* azTl = xnb + 3*2097152;

  hipMemsetAsync(cs, 0, BH*M_*sizeof(float), stream);
  ln2_k<<<4096,256,0,stream>>>(x, gamma, beta, xnb);
  twbw_k<<<dim3(32,8,1),256,0,stream>>>(w_qkv, wqkvT, w_out, woutT);
  gemm_qkv_k<<<dim3(12,128),256,0,stream>>>(xnb, wqkvT, qb, kb, vb);
  tbb_k<<<dim3(1,64,32),256,0,stream>>>(vb, vT, 4096, 64);
  lmk_k<<<2048,256,0,stream>>>(qb, kb, ql, kl, qlh, qll, klh, kll);
  attn2m_k<<<dim3(8,32),128,0,stream>>>(qlh, qll, klh, kll, a2f, a2h, a2l, cs);
  initz4_k<<<dim3(4,4,32),256,0,stream>>>(a2f, cs, z0h, z0l, z0Th, z0Tl);

  ushort_t *zch = z0h, *zcl = z0l, *zcTh = z0Th, *zcTl = z0Tl;
  ushort_t *znh = z1h, *znl = z1l, *znTh = z1Th, *znTl = z1Tl;
  dim3 nsg(4,4,32);
  for (int it=0; it<6; it++){
    // az = a2@z
    ns3_k<false,true,true,false><<<nsg,256,0,stream>>>(a2h, a2l, zcTh, zcTl,
        0.f, -1.f, azh, azl, azTh, azTl, (float*)nullptr);
    // t1 = 7az - az@az
    ns3_k<true,false,true,false><<<nsg,256,0,stream>>>(azh, azl, azTh, azTl,
        7.f, 1.f, (ushort_t*)nullptr, (ushort_t*)nullptr, t1Th, t1Tl, (float*)nullptr);
    // t2 = 15az - az@t1
    ns3_k<true,false,true,false><<<nsg,256,0,stream>>>(azh, azl, t1Th, t1Tl,
        15.f, 1.f, (ushort_t*)nullptr, (ushort_t*)nullptr, t2Th, t2Tl, (float*)nullptr);
    // z' = 0.25*(13z - z@t2)
    if (it < 5)
      ns3_k<true,true,true,false><<<nsg,256,0,stream>>>(zch, zcl, t2Th, t2Tl,
          13.f, 0.25f, znh, znl, znTh, znTl, (float*)nullptr);
    else
      ns3_k<true,true,true,true><<<nsg,256,0,stream>>>(zch, zcl, t2Th, t2Tl,
          13.f, 0.25f, znh, znl, znTh, znTl, zf);
    { ushort_t* tp;
      tp=zch; zch=znh; znh=tp;  tp=zcl; zcl=znl; znl=tp;
      tp=zcTh; zcTh=znTh; znTh=tp;  tp=zcTl; zcTl=znTl; znTl=tp; }
  }

  attn9_k<4,false><<<dim3(4,16,32),256,0,stream>>>(qlh, kb, vT, M_, N_,
      up, mstat, lstat, (ushort_t*)nullptr, (const ushort_t*)nullptr, (const float*)nullptr);
  comb_k<<<2048,256,0,stream>>>(up, mstat, lstat, u);
  zu_k<<<2048,256,0,stream>>>(zf, u, wz);
  twb_k<<<dim3(1,4,32),256,0,stream>>>(wz, wzT, 256, 64);
  attn9_k<4,true><<<dim3(64,1,32),256,0,stream>>>(qb, klh, wzT, N_, M_,
      (float*)nullptr, (float*)nullptr, (float*)nullptr, ob, vb, conv_w);
  final3_k<<<dim3(8,128),256,0,stream>>>(ob, woutT, b_out, x, y);
}